// Round 18
// baseline (30.784 us; speedup 1.0000x reference)
//
#include <hip/hip_runtime.h>
#include <math.h>

#define KG_B    16384
#define KG_D    128
#define KG_NR   24
#define KG_TM   64                        // elements per block (doubled)
#define KG_BPAD (KG_B + KG_NR * KG_TM)    // 17920
#define KG_NGRP (KG_BPAD / KG_TM)         // 280
#define KG_HB   16                        // sort blocks (1024 thr each)

// ws ints: perm[17920] | bsum[280](f32) | segrel[280] | hS[17920] | pS[17920] | nS[17920]
// preW @ byte 393216
#define WS_BSUM   KG_BPAD
#define WS_SEGREL (KG_BPAD + KG_NGRP)
#define WS_HS     (KG_BPAD + 2 * KG_NGRP)
#define WS_PS     (WS_HS + KG_BPAD)
#define WS_NS     (WS_PS + KG_BPAD)
#define WS_PREW_BYTES 393216

typedef __attribute__((ext_vector_type(8))) short bf16x8;
typedef __attribute__((ext_vector_type(4))) float f32x4;

__device__ __forceinline__ unsigned bf16r(float f) {
    return (__float_as_uint(f) + 0x8000u) >> 16;
}
__device__ __forceinline__ unsigned pack2(float lo, float hi) {
    return bf16r(lo) | (bf16r(hi) << 16);
}

// ---- K1: blocks 0..15 = self-contained sort (R17-proven: LDS-atomic
//      histogram of all chunks + ballot-rank scatter of own chunk);
//      blocks 16..39 = W^T bf16 prep (plain col-major). ----
__global__ __launch_bounds__(1024) void kg_sort_prep(
    const int* __restrict__ r,   const float* __restrict__ M,
    const int* __restrict__ h,   const int* __restrict__ pt,
    const int* __restrict__ nt,
    int* __restrict__ perm,      int* __restrict__ segrel,
    int* __restrict__ hS,        int* __restrict__ pS,
    int* __restrict__ nS,        unsigned short* __restrict__ preW)
{
    const int t = threadIdx.x;

    if (blockIdx.x >= KG_HB) {
        __shared__ __align__(16) unsigned short sWp[KG_D * KG_D];   // 32 KB
        const int k  = blockIdx.x - KG_HB;
        const int e  = t >> 3;
        const int c0 = (t & 7) * 16;
        const float* src = M + ((size_t)k << 14) + (size_t)e * KG_D + c0;
        float4 rw[4];
#pragma unroll
        for (int f = 0; f < 4; ++f) rw[f] = ((const float4*)src)[f];
#pragma unroll
        for (int dc = 0; dc < 16; ++dc) {
            const int col = c0 + dc;
            const float v = ((const float*)&rw[0])[dc];
            sWp[col * KG_D + e] = (unsigned short)bf16r(v);
        }
        __syncthreads();
        uint4* dst = (uint4*)(preW + ((size_t)k << 14));
        const uint4* s4 = (const uint4*)sWp;
        dst[2 * t]     = s4[2 * t];
        dst[2 * t + 1] = s4[2 * t + 1];
        return;
    }

    __shared__ int cnt[16][25];
    __shared__ int wcnt[16][25];
    __shared__ int wbase[16][25];
    __shared__ int tot[24], myb[24], pb0[24];
    __shared__ int padtot_s;

    const int j    = blockIdx.x;
    const int w    = t >> 6;
    const int lane = t & 63;

    // Phase A: full [16][24] histogram via LDS atomics
    int* cz = &cnt[0][0];
    for (int i = t; i < 16 * 25; i += 1024) cz[i] = 0;
    __syncthreads();
    int kt[16];
#pragma unroll
    for (int c = 0; c < 16; ++c) kt[c] = r[c * 1024 + t];
#pragma unroll
    for (int c = 0; c < 16; ++c) atomicAdd(&cnt[c][kt[c]], 1);
    __syncthreads();

    // Phase B: bases (quantum = KG_TM = 64)
    if (t < 24) {
        int s2 = 0, mb = 0;
        for (int j2 = 0; j2 < KG_HB; ++j2) {
            const int c = cnt[j2][t];
            s2 += c;
            if (j2 < j) mb += c;
        }
        tot[t] = s2;
        myb[t] = mb;
    }
    __syncthreads();
    if (t == 0) {
        int run = 0;
        for (int k2 = 0; k2 < 24; ++k2) {
            pb0[k2] = run;
            run += (tot[k2] + (KG_TM - 1)) & ~(KG_TM - 1);
        }
        padtot_s = run;
    }
    __syncthreads();

    // Phase C: ballot-rank scatter of own chunk j
    const int elem = j * 1024 + t;
    const int k = r[elem];
    unsigned long long mym = 0;
#pragma unroll
    for (int b = 0; b < 24; ++b) {
        const unsigned long long m = __ballot(k == b);
        if (k == b) mym = m;
        if (lane == 0) wcnt[w][b] = (int)__popcll(m);
    }
    const int rank_w = (int)__popcll(mym & ((1ull << lane) - 1ull));
    __syncthreads();
    if (t < 24) {
        int s = 0;
        for (int w2 = 0; w2 < 16; ++w2) { wbase[w2][t] = s; s += wcnt[w2][t]; }
    }
    __syncthreads();

    const int pos = pb0[k] + myb[k] + wbase[w][k] + rank_w;
    perm[pos] = elem;
    hS[pos]   = h[elem];
    pS[pos]   = pt[elem];
    nS[pos]   = nt[elem];
    if ((pos & (KG_TM - 1)) == 0) segrel[pos >> 6] = k;

    // Phase D (block 0): fill all padding
    if (j == 0) {
        if (t < 24) {
            const int e0 = pb0[t] + tot[t];
            const int e1 = pb0[t] + ((tot[t] + (KG_TM - 1)) & ~(KG_TM - 1));
            for (int p = e0; p < e1; ++p) {
                perm[p] = -1; hS[p] = 0; pS[p] = 0; nS[p] = 0;
            }
        }
        const int padtot = padtot_s;
        for (int i = padtot + t; i < KG_BPAD; i += 1024) {
            perm[i] = -1; hS[i] = 0; pS[i] = 0; nS[i] = 0;
        }
        for (int g = (padtot >> 6) + t; g < KG_NGRP; g += 1024)
            segrel[g] = -1;
    }
}

// ---- K2: MFMA main. Block = 64 same-relation elements, 8 waves of 64:
//      wave wv -> rows (wv&3)*16..+15, cols (wv>>2)*64..+63.
//      B read direct from L2-resident preW (R9-proven). ----
__global__ __launch_bounds__(512, 2) void kg_main(
    const float* __restrict__ ent, const float* __restrict__ rel,
    const unsigned short* __restrict__ preW,
    const int* __restrict__ hS,    const int* __restrict__ pS,
    const int* __restrict__ nS,    const int* __restrict__ segrel,
    const int* __restrict__ perm,  float* __restrict__ bsum)
{
    __shared__ __align__(16) unsigned short sX[3 * KG_TM * KG_D];   // 48 KB
    __shared__ float sScr[2][KG_TM][4];                             // 2 KB

    const int tid   = threadIdx.x;
    const int slot0 = blockIdx.x * KG_TM;
    const int rb    = __builtin_amdgcn_readfirstlane(segrel[blockIdx.x]);
    if (rb < 0) {
        if (tid == 0) bsum[blockIdx.x] = 0.f;
        return;
    }

    const int l   = tid & 63;
    const int wv  = tid >> 6;              // 0..7
    const int rt  = wv & 3;                // row-tile (16 rows)
    const int chs = wv >> 2;               // column half (64 cols)
    const int li  = l & 15;
    const int kq  = l >> 4;

    const unsigned short* __restrict__ preWk = preW + ((size_t)rb << 14);
    const float* relrow = rel + (size_t)rb * KG_D + chs * 64;
    float relv[4];
#pragma unroll
    for (int n = 0; n < 4; ++n) relv[n] = relrow[n * 16 + li];

    // ---- stage X: thread t -> row g=t>>3 (0..63), 16 dims at e0=(t&7)*16 ----
    {
        const int g  = tid >> 3;
        const int e0 = (tid & 7) * 16;
        const int idx3[3] = { hS[slot0 + g], pS[slot0 + g], nS[slot0 + g] };
        const int sw = (g & 7) << 3;
#pragma unroll
        for (int t3 = 0; t3 < 3; ++t3) {
            const float* src = ent + (size_t)idx3[t3] * KG_D + e0;
            const float4 f0 = ((const float4*)src)[0];
            const float4 f1 = ((const float4*)src)[1];
            const float4 f2 = ((const float4*)src)[2];
            const float4 f3 = ((const float4*)src)[3];
            uint4 u0, u1;
            u0.x = pack2(f0.x, f0.y); u0.y = pack2(f0.z, f0.w);
            u0.z = pack2(f1.x, f1.y); u0.w = pack2(f1.z, f1.w);
            u1.x = pack2(f2.x, f2.y); u1.y = pack2(f2.z, f2.w);
            u1.z = pack2(f3.x, f3.y); u1.w = pack2(f3.z, f3.w);
            unsigned short* base = sX + t3 * (KG_TM * KG_D) + g * KG_D;
            *(uint4*)(base + ((e0    ) ^ sw)) = u0;
            *(uint4*)(base + ((e0 + 8) ^ sw)) = u1;
        }
    }
    __syncthreads();

    const int ar  = rt * 16 + li;          // element row in block (0..63)
    const int asw = (ar & 7) << 3;

    f32x4 accf[3][4];
#pragma unroll
    for (int t3 = 0; t3 < 3; ++t3)
#pragma unroll
        for (int n = 0; n < 4; ++n) accf[t3][n] = (f32x4)0.f;

#pragma unroll
    for (int kk = 0; kk < 4; ++kk) {       // K chunks of 32
        const int e0 = kk * 32 + kq * 8;
        bf16x8 af[3];
#pragma unroll
        for (int t3 = 0; t3 < 3; ++t3)
            af[t3] = *(const bf16x8*)&sX[t3 * (KG_TM * KG_D) + ar * KG_D + (e0 ^ asw)];
#pragma unroll
        for (int n = 0; n < 4; ++n) {
            const int col = chs * 64 + n * 16 + li;
            const bf16x8 bfr = *(const bf16x8*)&preWk[col * KG_D + e0];
            accf[0][n] = __builtin_amdgcn_mfma_f32_16x16x32_bf16(af[0], bfr, accf[0][n], 0, 0, 0);
            accf[1][n] = __builtin_amdgcn_mfma_f32_16x16x32_bf16(af[1], bfr, accf[1][n], 0, 0, 0);
            accf[2][n] = __builtin_amdgcn_mfma_f32_16x16x32_bf16(af[2], bfr, accf[2][n], 0, 0, 0);
        }
    }

    // ---- epilogue: C/D layout col=lane&15, row=(lane>>4)*4+reg ----
    float ps[4] = {0,0,0,0}, ns[4] = {0,0,0,0}, sq[4] = {0,0,0,0};
#pragma unroll
    for (int n = 0; n < 4; ++n) {
        const float rv = relv[n];
#pragma unroll
        for (int j = 0; j < 4; ++j) {
            const float va = accf[0][n][j];
            const float vp = accf[1][n][j];
            const float vn = accf[2][n][j];
            const float s  = va + rv;
            const float dp = s - vp;
            const float dn = s - vn;
            ps[j] += dp * dp;
            ns[j] += dn * dn;
            sq[j] += va * va + vp * vp + vn * vn + rv * rv;
        }
    }
#pragma unroll
    for (int j = 0; j < 4; ++j)
#pragma unroll
        for (int m = 1; m < 16; m <<= 1) {
            ps[j] += __shfl_xor(ps[j], m);
            ns[j] += __shfl_xor(ns[j], m);
            sq[j] += __shfl_xor(sq[j], m);
        }

    if (li == 0) {
#pragma unroll
        for (int j = 0; j < 4; ++j) {
            const int row = rt * 16 + kq * 4 + j;
            sScr[chs][row][0] = ps[j];
            sScr[chs][row][1] = ns[j];
            sScr[chs][row][2] = sq[j];
        }
    }
    __syncthreads();

    if (tid < KG_TM) {
        const int row = tid;
        const float P = sScr[0][row][0] + sScr[1][row][0];
        const float N = sScr[0][row][1] + sScr[1][row][1];
        const float S = sScr[0][row][2] + sScr[1][row][2];
        float term = 0.f;
        if (perm[slot0 + row] >= 0) {
            const float x = P - N;                            // pos - neg
            term = fmaxf(x, 0.f) + log1pf(expf(-fabsf(x)))    // softplus
                 + 5e-6f * S;                                 // lambda/2 * l2
        }
#pragma unroll
        for (int off = 32; off > 0; off >>= 1) term += __shfl_down(term, off);
        if (tid == 0) bsum[blockIdx.x] = term;
    }
}

// ---- K3: deterministic final reduction over 280 block sums ----
__global__ __launch_bounds__(256) void kg_final(const float* __restrict__ bsum,
                                                float* __restrict__ out) {
    __shared__ float s[256];
    const int t = threadIdx.x;
    float acc = 0.f;
    for (int i = t; i < KG_NGRP; i += 256) acc += bsum[i];
    s[t] = acc;
    __syncthreads();
    for (int off = 128; off > 0; off >>= 1) {
        if (t < off) s[t] += s[t + off];
        __syncthreads();
    }
    if (t == 0) out[0] = s[0] * (1.0f / (float)KG_B);
}

extern "C" void kernel_launch(void* const* d_in, const int* in_sizes, int n_in,
                              void* d_out, int out_size, void* d_ws, size_t ws_size,
                              hipStream_t stream) {
    const float* ent = (const float*)d_in[0];
    const float* rel = (const float*)d_in[1];
    const float* M   = (const float*)d_in[2];
    const int*   h   = (const int*)d_in[3];
    const int*   r   = (const int*)d_in[4];
    const int*   pt  = (const int*)d_in[5];
    const int*   nt  = (const int*)d_in[6];

    int*            perm   = (int*)d_ws;
    float*          bsum   = (float*)d_ws + WS_BSUM;
    int*            segrel = (int*)d_ws + WS_SEGREL;
    int*            hS     = (int*)d_ws + WS_HS;
    int*            pS     = (int*)d_ws + WS_PS;
    int*            nS     = (int*)d_ws + WS_NS;
    unsigned short* preW   = (unsigned short*)((char*)d_ws + WS_PREW_BYTES);
    float*          out    = (float*)d_out;

    kg_sort_prep<<<KG_HB + KG_NR, 1024, 0, stream>>>(r, M, h, pt, nt,
                                                     perm, segrel, hS, pS, nS, preW);
    kg_main     <<<KG_NGRP, 512, 0, stream>>>(ent, rel, preW, hS, pS, nS,
                                              segrel, perm, bsum);
    kg_final    <<<1, 256, 0, stream>>>(bsum, out);
}

// Round 19
// 27.997 us; speedup vs baseline: 1.0995x; 1.0995x over previous
//
#include <hip/hip_runtime.h>
#include <math.h>

#define KG_B    16384
#define KG_D    128
#define KG_NR   24
#define KG_TM   32                        // elements per block
#define KG_BPAD (KG_B + KG_NR * KG_TM)    // 17152
#define KG_NGRP (KG_BPAD / KG_TM)         // 536
#define KG_HB   16                        // sort blocks (1024 thr each)

// ws ints: perm[17152] | bsum[536](f32) | segrel[536] | hS[17152] | pS[17152] | nS[17152]
// preW @ byte 393216
#define WS_BSUM   KG_BPAD
#define WS_SEGREL (KG_BPAD + KG_NGRP)
#define WS_HS     (KG_BPAD + 2 * KG_NGRP)
#define WS_PS     (WS_HS + KG_BPAD)
#define WS_NS     (WS_PS + KG_BPAD)
#define WS_PREW_BYTES 393216

typedef __attribute__((ext_vector_type(8))) short bf16x8;
typedef __attribute__((ext_vector_type(4))) float f32x4;

__device__ __forceinline__ unsigned bf16r(float f) {
    return (__float_as_uint(f) + 0x8000u) >> 16;
}
__device__ __forceinline__ unsigned pack2(float lo, float hi) {
    return bf16r(lo) | (bf16r(hi) << 16);
}

// ---- K1: blocks 0..15 = self-contained sort (R17-proven); blocks 16..39 =
//      W^T bf16 prep (plain col-major: preW[k][col*128+e] = bf16(W[k][e][col])). ----
__global__ __launch_bounds__(1024) void kg_sort_prep(
    const int* __restrict__ r,   const float* __restrict__ M,
    const int* __restrict__ h,   const int* __restrict__ pt,
    const int* __restrict__ nt,
    int* __restrict__ perm,      int* __restrict__ segrel,
    int* __restrict__ hS,        int* __restrict__ pS,
    int* __restrict__ nS,        unsigned short* __restrict__ preW)
{
    const int t = threadIdx.x;

    if (blockIdx.x >= KG_HB) {
        __shared__ __align__(16) unsigned short sWp[KG_D * KG_D];   // 32 KB
        const int k  = blockIdx.x - KG_HB;
        const int e  = t >> 3;
        const int c0 = (t & 7) * 16;
        const float* src = M + ((size_t)k << 14) + (size_t)e * KG_D + c0;
        float4 rw[4];
#pragma unroll
        for (int f = 0; f < 4; ++f) rw[f] = ((const float4*)src)[f];
#pragma unroll
        for (int dc = 0; dc < 16; ++dc) {
            const int col = c0 + dc;
            const float v = ((const float*)&rw[0])[dc];
            sWp[col * KG_D + e] = (unsigned short)bf16r(v);
        }
        __syncthreads();
        uint4* dst = (uint4*)(preW + ((size_t)k << 14));
        const uint4* s4 = (const uint4*)sWp;
        dst[2 * t]     = s4[2 * t];
        dst[2 * t + 1] = s4[2 * t + 1];
        return;
    }

    __shared__ int cnt[16][25];
    __shared__ int wcnt[16][25];
    __shared__ int wbase[16][25];
    __shared__ int tot[24], myb[24], pb0[24];
    __shared__ int padtot_s;

    const int j    = blockIdx.x;
    const int w    = t >> 6;
    const int lane = t & 63;

    // Phase A: full [16][24] histogram via LDS atomics
    int* cz = &cnt[0][0];
    for (int i = t; i < 16 * 25; i += 1024) cz[i] = 0;
    __syncthreads();
    int kt[16];
#pragma unroll
    for (int c = 0; c < 16; ++c) kt[c] = r[c * 1024 + t];
#pragma unroll
    for (int c = 0; c < 16; ++c) atomicAdd(&cnt[c][kt[c]], 1);
    __syncthreads();

    // Phase B: bases
    if (t < 24) {
        int s2 = 0, mb = 0;
        for (int j2 = 0; j2 < KG_HB; ++j2) {
            const int c = cnt[j2][t];
            s2 += c;
            if (j2 < j) mb += c;
        }
        tot[t] = s2;
        myb[t] = mb;
    }
    __syncthreads();
    if (t == 0) {
        int run = 0;
        for (int k2 = 0; k2 < 24; ++k2) {
            pb0[k2] = run;
            run += (tot[k2] + (KG_TM - 1)) & ~(KG_TM - 1);
        }
        padtot_s = run;
    }
    __syncthreads();

    // Phase C: ballot-rank scatter of own chunk j
    const int elem = j * 1024 + t;
    const int k = r[elem];
    unsigned long long mym = 0;
#pragma unroll
    for (int b = 0; b < 24; ++b) {
        const unsigned long long m = __ballot(k == b);
        if (k == b) mym = m;
        if (lane == 0) wcnt[w][b] = (int)__popcll(m);
    }
    const int rank_w = (int)__popcll(mym & ((1ull << lane) - 1ull));
    __syncthreads();
    if (t < 24) {
        int s = 0;
        for (int w2 = 0; w2 < 16; ++w2) { wbase[w2][t] = s; s += wcnt[w2][t]; }
    }
    __syncthreads();

    const int pos = pb0[k] + myb[k] + wbase[w][k] + rank_w;
    perm[pos] = elem;
    hS[pos]   = h[elem];
    pS[pos]   = pt[elem];
    nS[pos]   = nt[elem];
    if ((pos & (KG_TM - 1)) == 0) segrel[pos >> 5] = k;

    // Phase D (block 0): fill all padding
    if (j == 0) {
        if (t < 24) {
            const int e0 = pb0[t] + tot[t];
            const int e1 = pb0[t] + ((tot[t] + (KG_TM - 1)) & ~(KG_TM - 1));
            for (int p = e0; p < e1; ++p) {
                perm[p] = -1; hS[p] = 0; pS[p] = 0; nS[p] = 0;
            }
        }
        const int padtot = padtot_s;
        for (int i = padtot + t; i < KG_BPAD; i += 1024) {
            perm[i] = -1; hS[i] = 0; pS[i] = 0; nS[i] = 0;
        }
        for (int g = (padtot >> 5) + t; g < KG_NGRP; g += 1024)
            segrel[g] = -1;
    }
}

// ---- K2: MFMA main. R17 structure but NO bpre register preload (B read
//      direct from L2-resident preW — R9-proven neutral) -> VGPR drops,
//      __launch_bounds__(256,4) -> 4 blocks/CU (16 waves) for gather hiding. ----
__global__ __launch_bounds__(256, 4) void kg_main(
    const float* __restrict__ ent, const float* __restrict__ rel,
    const unsigned short* __restrict__ preW,
    const int* __restrict__ hS,    const int* __restrict__ pS,
    const int* __restrict__ nS,    const int* __restrict__ segrel,
    const int* __restrict__ perm,  float* __restrict__ bsum)
{
    __shared__ __align__(16) unsigned short sX[3 * KG_TM * KG_D];   // 24 KB
    __shared__ float sScr[2][KG_TM][4];

    const int tid   = threadIdx.x;
    const int slot0 = blockIdx.x * KG_TM;
    const int rb    = __builtin_amdgcn_readfirstlane(segrel[blockIdx.x]);
    if (rb < 0) {
        if (tid == 0) bsum[blockIdx.x] = 0.f;
        return;
    }

    const int l   = tid & 63;
    const int wv  = tid >> 6;
    const int rt  = wv & 1;
    const int chs = wv >> 1;
    const int li  = l & 15;
    const int kq  = l >> 4;

    const unsigned short* __restrict__ preWk = preW + ((size_t)rb << 14);
    const float* relrow = rel + (size_t)rb * KG_D + chs * 64;
    float relv[4];
#pragma unroll
    for (int n = 0; n < 4; ++n) relv[n] = relrow[n * 16 + li];

    // ---- stage X: thread t -> row g=t>>3, 16 dims at e0=(t&7)*16 ----
    {
        const int g  = tid >> 3;
        const int e0 = (tid & 7) * 16;
        const int idx3[3] = { hS[slot0 + g], pS[slot0 + g], nS[slot0 + g] };
        const int sw = (g & 7) << 3;
#pragma unroll
        for (int t3 = 0; t3 < 3; ++t3) {
            const float* src = ent + (size_t)idx3[t3] * KG_D + e0;
            const float4 f0 = ((const float4*)src)[0];
            const float4 f1 = ((const float4*)src)[1];
            const float4 f2 = ((const float4*)src)[2];
            const float4 f3 = ((const float4*)src)[3];
            uint4 u0, u1;
            u0.x = pack2(f0.x, f0.y); u0.y = pack2(f0.z, f0.w);
            u0.z = pack2(f1.x, f1.y); u0.w = pack2(f1.z, f1.w);
            u1.x = pack2(f2.x, f2.y); u1.y = pack2(f2.z, f2.w);
            u1.z = pack2(f3.x, f3.y); u1.w = pack2(f3.z, f3.w);
            unsigned short* base = sX + t3 * (KG_TM * KG_D) + g * KG_D;
            *(uint4*)(base + ((e0    ) ^ sw)) = u0;
            *(uint4*)(base + ((e0 + 8) ^ sw)) = u1;
        }
    }
    __syncthreads();

    const int ar  = rt * 16 + li;
    const int asw = (ar & 7) << 3;

    f32x4 accf[3][4];
#pragma unroll
    for (int t3 = 0; t3 < 3; ++t3)
#pragma unroll
        for (int n = 0; n < 4; ++n) accf[t3][n] = (f32x4)0.f;

#pragma unroll
    for (int kk = 0; kk < 4; ++kk) {       // K chunks of 32
        const int e0 = kk * 32 + kq * 8;
        bf16x8 af[3];
#pragma unroll
        for (int t3 = 0; t3 < 3; ++t3)
            af[t3] = *(const bf16x8*)&sX[t3 * (KG_TM * KG_D) + ar * KG_D + (e0 ^ asw)];
#pragma unroll
        for (int n = 0; n < 4; ++n) {
            const int col = chs * 64 + n * 16 + li;
            const bf16x8 bfr = *(const bf16x8*)&preWk[col * KG_D + e0];
            accf[0][n] = __builtin_amdgcn_mfma_f32_16x16x32_bf16(af[0], bfr, accf[0][n], 0, 0, 0);
            accf[1][n] = __builtin_amdgcn_mfma_f32_16x16x32_bf16(af[1], bfr, accf[1][n], 0, 0, 0);
            accf[2][n] = __builtin_amdgcn_mfma_f32_16x16x32_bf16(af[2], bfr, accf[2][n], 0, 0, 0);
        }
    }

    // ---- epilogue: C/D layout col=lane&15, row=(lane>>4)*4+reg ----
    float ps[4] = {0,0,0,0}, ns[4] = {0,0,0,0}, sq[4] = {0,0,0,0};
#pragma unroll
    for (int n = 0; n < 4; ++n) {
        const float rv = relv[n];
#pragma unroll
        for (int j = 0; j < 4; ++j) {
            const float va = accf[0][n][j];
            const float vp = accf[1][n][j];
            const float vn = accf[2][n][j];
            const float s  = va + rv;
            const float dp = s - vp;
            const float dn = s - vn;
            ps[j] += dp * dp;
            ns[j] += dn * dn;
            sq[j] += va * va + vp * vp + vn * vn + rv * rv;
        }
    }
#pragma unroll
    for (int j = 0; j < 4; ++j)
#pragma unroll
        for (int m = 1; m < 16; m <<= 1) {
            ps[j] += __shfl_xor(ps[j], m);
            ns[j] += __shfl_xor(ns[j], m);
            sq[j] += __shfl_xor(sq[j], m);
        }

    if (li == 0) {
#pragma unroll
        for (int j = 0; j < 4; ++j) {
            const int row = rt * 16 + kq * 4 + j;
            sScr[chs][row][0] = ps[j];
            sScr[chs][row][1] = ns[j];
            sScr[chs][row][2] = sq[j];
        }
    }
    __syncthreads();

    if (tid < 64) {
        float term = 0.f;
        if (tid < KG_TM) {
            const int row = tid;
            const float P = sScr[0][row][0] + sScr[1][row][0];
            const float N = sScr[0][row][1] + sScr[1][row][1];
            const float S = sScr[0][row][2] + sScr[1][row][2];
            if (perm[slot0 + row] >= 0) {
                const float x = P - N;                            // pos - neg
                term = fmaxf(x, 0.f) + log1pf(expf(-fabsf(x)))    // softplus
                     + 5e-6f * S;                                 // lambda/2 * l2
            }
        }
#pragma unroll
        for (int off = 16; off > 0; off >>= 1) term += __shfl_down(term, off);
        if (tid == 0) bsum[blockIdx.x] = term;
    }
}

// ---- K3: deterministic final reduction over 536 block sums ----
__global__ __launch_bounds__(256) void kg_final(const float* __restrict__ bsum,
                                                float* __restrict__ out) {
    __shared__ float s[256];
    const int t = threadIdx.x;
    float acc = 0.f;
    for (int i = t; i < KG_NGRP; i += 256) acc += bsum[i];
    s[t] = acc;
    __syncthreads();
    for (int off = 128; off > 0; off >>= 1) {
        if (t < off) s[t] += s[t + off];
        __syncthreads();
    }
    if (t == 0) out[0] = s[0] * (1.0f / (float)KG_B);
}

extern "C" void kernel_launch(void* const* d_in, const int* in_sizes, int n_in,
                              void* d_out, int out_size, void* d_ws, size_t ws_size,
                              hipStream_t stream) {
    const float* ent = (const float*)d_in[0];
    const float* rel = (const float*)d_in[1];
    const float* M   = (const float*)d_in[2];
    const int*   h   = (const int*)d_in[3];
    const int*   r   = (const int*)d_in[4];
    const int*   pt  = (const int*)d_in[5];
    const int*   nt  = (const int*)d_in[6];

    int*            perm   = (int*)d_ws;
    float*          bsum   = (float*)d_ws + WS_BSUM;
    int*            segrel = (int*)d_ws + WS_SEGREL;
    int*            hS     = (int*)d_ws + WS_HS;
    int*            pS     = (int*)d_ws + WS_PS;
    int*            nS     = (int*)d_ws + WS_NS;
    unsigned short* preW   = (unsigned short*)((char*)d_ws + WS_PREW_BYTES);
    float*          out    = (float*)d_out;

    kg_sort_prep<<<KG_HB + KG_NR, 1024, 0, stream>>>(r, M, h, pt, nt,
                                                     perm, segrel, hS, pS, nS, preW);
    kg_main     <<<KG_NGRP, 256, 0, stream>>>(ent, rel, preW, hS, pS, nS,
                                              segrel, perm, bsum);
    kg_final    <<<1, 256, 0, stream>>>(bsum, out);
}

// Round 20
// 25.679 us; speedup vs baseline: 1.1988x; 1.0903x over previous
//
#include <hip/hip_runtime.h>
#include <math.h>

#define KG_B    16384
#define KG_D    128
#define KG_NR   24
#define KG_TM   32                        // elements per block
#define KG_BPAD (KG_B + KG_NR * KG_TM)    // 17152
#define KG_NGRP (KG_BPAD / KG_TM)         // 536
#define KG_HB   16                        // sort blocks (1024 thr each)

// ws: int4 rec[17152] @ 0 (274432 B) | float bsum[536] @ 274432 | int segrel[536] @ 276576
//     | ushort preW[24*16384] @ byte 393216
#define WS_BSUM_BYTES   274432
#define WS_SEGREL_BYTES 276576
#define WS_PREW_BYTES   393216

typedef __attribute__((ext_vector_type(8))) short bf16x8;
typedef __attribute__((ext_vector_type(4))) float f32x4;

__device__ __forceinline__ unsigned bf16r(float f) {
    return (__float_as_uint(f) + 0x8000u) >> 16;
}
__device__ __forceinline__ unsigned pack2(float lo, float hi) {
    return bf16r(lo) | (bf16r(hi) << 16);
}

// ---- K1: blocks 0..15 = self-contained sort (R17-proven histogram+ballot
//      scatter), writing ONE interleaved int4 record {elem,h,pt,nt} per slot;
//      blocks 16..39 = W^T bf16 prep (plain col-major). ----
__global__ __launch_bounds__(1024) void kg_sort_prep(
    const int* __restrict__ r,   const float* __restrict__ M,
    const int* __restrict__ h,   const int* __restrict__ pt,
    const int* __restrict__ nt,
    int4* __restrict__ rec,      int* __restrict__ segrel,
    unsigned short* __restrict__ preW)
{
    const int t = threadIdx.x;

    if (blockIdx.x >= KG_HB) {
        __shared__ __align__(16) unsigned short sWp[KG_D * KG_D];   // 32 KB
        const int k  = blockIdx.x - KG_HB;
        const int e  = t >> 3;
        const int c0 = (t & 7) * 16;
        const float* src = M + ((size_t)k << 14) + (size_t)e * KG_D + c0;
        float4 rw[4];
#pragma unroll
        for (int f = 0; f < 4; ++f) rw[f] = ((const float4*)src)[f];
#pragma unroll
        for (int dc = 0; dc < 16; ++dc) {
            const int col = c0 + dc;
            const float v = ((const float*)&rw[0])[dc];
            sWp[col * KG_D + e] = (unsigned short)bf16r(v);
        }
        __syncthreads();
        uint4* dst = (uint4*)(preW + ((size_t)k << 14));
        const uint4* s4 = (const uint4*)sWp;
        dst[2 * t]     = s4[2 * t];
        dst[2 * t + 1] = s4[2 * t + 1];
        return;
    }

    __shared__ int cnt[16][25];
    __shared__ int wcnt[16][25];
    __shared__ int wbase[16][25];
    __shared__ int tot[24], myb[24], pb0[24];
    __shared__ int padtot_s;

    const int j    = blockIdx.x;
    const int w    = t >> 6;
    const int lane = t & 63;

    // Phase A: full [16][24] histogram via LDS atomics
    int* cz = &cnt[0][0];
    for (int i = t; i < 16 * 25; i += 1024) cz[i] = 0;
    __syncthreads();
    int kt[16];
#pragma unroll
    for (int c = 0; c < 16; ++c) kt[c] = r[c * 1024 + t];
#pragma unroll
    for (int c = 0; c < 16; ++c) atomicAdd(&cnt[c][kt[c]], 1);
    __syncthreads();

    // Phase B: bases
    if (t < 24) {
        int s2 = 0, mb = 0;
        for (int j2 = 0; j2 < KG_HB; ++j2) {
            const int c = cnt[j2][t];
            s2 += c;
            if (j2 < j) mb += c;
        }
        tot[t] = s2;
        myb[t] = mb;
    }
    __syncthreads();
    if (t == 0) {
        int run = 0;
        for (int k2 = 0; k2 < 24; ++k2) {
            pb0[k2] = run;
            run += (tot[k2] + (KG_TM - 1)) & ~(KG_TM - 1);
        }
        padtot_s = run;
    }
    __syncthreads();

    // Phase C: ballot-rank scatter of own chunk j — ONE int4 store/element
    const int elem = j * 1024 + t;
    const int k = r[elem];
    unsigned long long mym = 0;
#pragma unroll
    for (int b = 0; b < 24; ++b) {
        const unsigned long long m = __ballot(k == b);
        if (k == b) mym = m;
        if (lane == 0) wcnt[w][b] = (int)__popcll(m);
    }
    const int rank_w = (int)__popcll(mym & ((1ull << lane) - 1ull));
    __syncthreads();
    if (t < 24) {
        int s = 0;
        for (int w2 = 0; w2 < 16; ++w2) { wbase[w2][t] = s; s += wcnt[w2][t]; }
    }
    __syncthreads();

    const int pos = pb0[k] + myb[k] + wbase[w][k] + rank_w;
    rec[pos] = make_int4(elem, h[elem], pt[elem], nt[elem]);
    if ((pos & (KG_TM - 1)) == 0) segrel[pos >> 5] = k;

    // Phase D (block 0): fill all padding
    if (j == 0) {
        const int4 padrec = make_int4(-1, 0, 0, 0);
        if (t < 24) {
            const int e0 = pb0[t] + tot[t];
            const int e1 = pb0[t] + ((tot[t] + (KG_TM - 1)) & ~(KG_TM - 1));
            for (int p = e0; p < e1; ++p) rec[p] = padrec;
        }
        const int padtot = padtot_s;
        for (int i = padtot + t; i < KG_BPAD; i += 1024) rec[i] = padrec;
        for (int g = (padtot >> 5) + t; g < KG_NGRP; g += 1024)
            segrel[g] = -1;
    }
}

// ---- K2: MFMA main (R17-best structure: bpre preload, (256,3)); staging
//      indices + validity from ONE int4 record load per row. ----
__global__ __launch_bounds__(256, 3) void kg_main(
    const float* __restrict__ ent, const float* __restrict__ rel,
    const unsigned short* __restrict__ preW,
    const int4* __restrict__ rec,  const int* __restrict__ segrel,
    float* __restrict__ bsum)
{
    __shared__ __align__(16) unsigned short sX[3 * KG_TM * KG_D];   // 24 KB
    __shared__ float sScr[2][KG_TM][4];

    const int tid   = threadIdx.x;
    const int slot0 = blockIdx.x * KG_TM;
    const int rb    = __builtin_amdgcn_readfirstlane(segrel[blockIdx.x]);
    if (rb < 0) {
        if (tid == 0) bsum[blockIdx.x] = 0.f;
        return;
    }

    const int l   = tid & 63;
    const int wv  = tid >> 6;
    const int rt  = wv & 1;
    const int chs = wv >> 1;
    const int li  = l & 15;
    const int kq  = l >> 4;

    // ---- pre-load ALL 16 B fragments + 4 rel values (hide under staging) ----
    const unsigned short* __restrict__ preWk = preW + ((size_t)rb << 14);
    bf16x8 bpre[4][4];
#pragma unroll
    for (int kk = 0; kk < 4; ++kk)
#pragma unroll
        for (int n = 0; n < 4; ++n)
            bpre[kk][n] = *(const bf16x8*)&preWk[(chs * 64 + n * 16 + li) * KG_D
                                                 + kk * 32 + kq * 8];
    const float* relrow = rel + (size_t)rb * KG_D + chs * 64;
    float relv[4];
#pragma unroll
    for (int n = 0; n < 4; ++n) relv[n] = relrow[n * 16 + li];

    // ---- stage X: thread t -> row g=t>>3, 16 dims at e0=(t&7)*16 ----
    {
        const int g  = tid >> 3;
        const int e0 = (tid & 7) * 16;
        const int4 rc = rec[slot0 + g];    // {elem, h, pt, nt} in one load
        const int idx3[3] = { rc.y, rc.z, rc.w };
        const int sw = (g & 7) << 3;
#pragma unroll
        for (int t3 = 0; t3 < 3; ++t3) {
            const float* src = ent + (size_t)idx3[t3] * KG_D + e0;
            const float4 f0 = ((const float4*)src)[0];
            const float4 f1 = ((const float4*)src)[1];
            const float4 f2 = ((const float4*)src)[2];
            const float4 f3 = ((const float4*)src)[3];
            uint4 u0, u1;
            u0.x = pack2(f0.x, f0.y); u0.y = pack2(f0.z, f0.w);
            u0.z = pack2(f1.x, f1.y); u0.w = pack2(f1.z, f1.w);
            u1.x = pack2(f2.x, f2.y); u1.y = pack2(f2.z, f2.w);
            u1.z = pack2(f3.x, f3.y); u1.w = pack2(f3.z, f3.w);
            unsigned short* base = sX + t3 * (KG_TM * KG_D) + g * KG_D;
            *(uint4*)(base + ((e0    ) ^ sw)) = u0;
            *(uint4*)(base + ((e0 + 8) ^ sw)) = u1;
        }
    }
    __syncthreads();

    const int ar  = rt * 16 + li;
    const int asw = (ar & 7) << 3;

    f32x4 accf[3][4];
#pragma unroll
    for (int t3 = 0; t3 < 3; ++t3)
#pragma unroll
        for (int n = 0; n < 4; ++n) accf[t3][n] = (f32x4)0.f;

#pragma unroll
    for (int kk = 0; kk < 4; ++kk) {       // K chunks of 32
        const int e0 = kk * 32 + kq * 8;
        bf16x8 af[3];
#pragma unroll
        for (int t3 = 0; t3 < 3; ++t3)
            af[t3] = *(const bf16x8*)&sX[t3 * (KG_TM * KG_D) + ar * KG_D + (e0 ^ asw)];
#pragma unroll
        for (int n = 0; n < 4; ++n) {
            accf[0][n] = __builtin_amdgcn_mfma_f32_16x16x32_bf16(af[0], bpre[kk][n], accf[0][n], 0, 0, 0);
            accf[1][n] = __builtin_amdgcn_mfma_f32_16x16x32_bf16(af[1], bpre[kk][n], accf[1][n], 0, 0, 0);
            accf[2][n] = __builtin_amdgcn_mfma_f32_16x16x32_bf16(af[2], bpre[kk][n], accf[2][n], 0, 0, 0);
        }
    }

    // ---- epilogue: C/D layout col=lane&15, row=(lane>>4)*4+reg ----
    float ps[4] = {0,0,0,0}, ns[4] = {0,0,0,0}, sq[4] = {0,0,0,0};
#pragma unroll
    for (int n = 0; n < 4; ++n) {
        const float rv = relv[n];
#pragma unroll
        for (int j = 0; j < 4; ++j) {
            const float va = accf[0][n][j];
            const float vp = accf[1][n][j];
            const float vn = accf[2][n][j];
            const float s  = va + rv;
            const float dp = s - vp;
            const float dn = s - vn;
            ps[j] += dp * dp;
            ns[j] += dn * dn;
            sq[j] += va * va + vp * vp + vn * vn + rv * rv;
        }
    }
#pragma unroll
    for (int j = 0; j < 4; ++j)
#pragma unroll
        for (int m = 1; m < 16; m <<= 1) {
            ps[j] += __shfl_xor(ps[j], m);
            ns[j] += __shfl_xor(ns[j], m);
            sq[j] += __shfl_xor(sq[j], m);
        }

    if (li == 0) {
#pragma unroll
        for (int j = 0; j < 4; ++j) {
            const int row = rt * 16 + kq * 4 + j;
            sScr[chs][row][0] = ps[j];
            sScr[chs][row][1] = ns[j];
            sScr[chs][row][2] = sq[j];
        }
    }
    __syncthreads();

    if (tid < 64) {
        float term = 0.f;
        if (tid < KG_TM) {
            const int row = tid;
            const float P = sScr[0][row][0] + sScr[1][row][0];
            const float N = sScr[0][row][1] + sScr[1][row][1];
            const float S = sScr[0][row][2] + sScr[1][row][2];
            if (rec[slot0 + row].x >= 0) {
                const float x = P - N;                            // pos - neg
                term = fmaxf(x, 0.f) + log1pf(expf(-fabsf(x)))    // softplus
                     + 5e-6f * S;                                 // lambda/2 * l2
            }
        }
#pragma unroll
        for (int off = 16; off > 0; off >>= 1) term += __shfl_down(term, off);
        if (tid == 0) bsum[blockIdx.x] = term;
    }
}

// ---- K3: deterministic final reduction over 536 block sums ----
__global__ __launch_bounds__(256) void kg_final(const float* __restrict__ bsum,
                                                float* __restrict__ out) {
    __shared__ float s[256];
    const int t = threadIdx.x;
    float acc = 0.f;
    for (int i = t; i < KG_NGRP; i += 256) acc += bsum[i];
    s[t] = acc;
    __syncthreads();
    for (int off = 128; off > 0; off >>= 1) {
        if (t < off) s[t] += s[t + off];
        __syncthreads();
    }
    if (t == 0) out[0] = s[0] * (1.0f / (float)KG_B);
}

extern "C" void kernel_launch(void* const* d_in, const int* in_sizes, int n_in,
                              void* d_out, int out_size, void* d_ws, size_t ws_size,
                              hipStream_t stream) {
    const float* ent = (const float*)d_in[0];
    const float* rel = (const float*)d_in[1];
    const float* M   = (const float*)d_in[2];
    const int*   h   = (const int*)d_in[3];
    const int*   r   = (const int*)d_in[4];
    const int*   pt  = (const int*)d_in[5];
    const int*   nt  = (const int*)d_in[6];

    int4*           rec    = (int4*)d_ws;
    float*          bsum   = (float*)((char*)d_ws + WS_BSUM_BYTES);
    int*            segrel = (int*)((char*)d_ws + WS_SEGREL_BYTES);
    unsigned short* preW   = (unsigned short*)((char*)d_ws + WS_PREW_BYTES);
    float*          out    = (float*)d_out;

    kg_sort_prep<<<KG_HB + KG_NR, 1024, 0, stream>>>(r, M, h, pt, nt,
                                                     rec, segrel, preW);
    kg_main     <<<KG_NGRP, 256, 0, stream>>>(ent, rel, preW, rec, segrel, bsum);
    kg_final    <<<1, 256, 0, stream>>>(bsum, out);
}